// Round 1
// baseline (1545.059 us; speedup 1.0000x reference)
//
#include <hip/hip_runtime.h>
#include <math.h>

// Problem constants
#define BATCH 64
#define N_ATOMS 512
#define NE 500
#define FIELD_DIM 256
#define E_DIM 64
#define HIDDEN 512
#define LATENT 256

// ---------------------------------------------------------------------------
// Generic tiled fp32 GEMM: C[M,N] = act( scale * (A @ W) + bias )
//   A: [M,K] row-major (batched via sA)
//   W: if !BT: [K,N] row-major; if BT: [N,K] row-major (i.e., C = A @ W^T)
//   bias: [N] or nullptr
// BM=BN=128, BK=16, 256 threads, 8x8 outputs/thread (split 2x2 blocks of 4x4).
// Only M may be a non-multiple of 128 (500, 32000, 32768); N,K always aligned.
// ---------------------------------------------------------------------------
template <int ACT, bool BT>
__global__ __launch_bounds__(256) void gemm_kernel(
    const float* __restrict__ A, const float* __restrict__ Wm,
    const float* __restrict__ bias, float* __restrict__ C,
    int M, int Nn, int K,
    long long sA, long long sW, long long sC, float scale)
{
    __shared__ float As[16][132];
    __shared__ float Bs[16][132];

    const int bz = blockIdx.z;
    A  += (long long)bz * sA;
    Wm += (long long)bz * sW;
    C  += (long long)bz * sC;

    const int m0 = blockIdx.y * 128;
    const int n0 = blockIdx.x * 128;
    const int t  = threadIdx.x;
    const int tx = t & 15;    // 0..15 -> N
    const int ty = t >> 4;    // 0..15 -> M

    float acc[8][8];
#pragma unroll
    for (int i = 0; i < 8; i++)
#pragma unroll
        for (int j = 0; j < 8; j++) acc[i][j] = 0.f;

    for (int k0 = 0; k0 < K; k0 += 16) {
        // --- A tile: 128 rows x 16 k, transposed into As[k][m]
#pragma unroll
        for (int j = 0; j < 2; j++) {
            int li  = t + j * 256;       // 0..511
            int row = li >> 2;           // 0..127
            int c4  = (li & 3) * 4;      // 0,4,8,12
            float4 av = make_float4(0.f, 0.f, 0.f, 0.f);
            if (m0 + row < M)
                av = *reinterpret_cast<const float4*>(A + (long long)(m0 + row) * K + k0 + c4);
            As[c4 + 0][row] = av.x;
            As[c4 + 1][row] = av.y;
            As[c4 + 2][row] = av.z;
            As[c4 + 3][row] = av.w;
        }
        // --- W tile
        if (!BT) {
            // W[K,N]: rows k0..k0+15, cols n0..n0+127 -> Bs[k][n]
#pragma unroll
            for (int j = 0; j < 2; j++) {
                int li  = t + j * 256;
                int row = li >> 5;           // 0..15
                int c4  = (li & 31) * 4;     // 0..124
                float4 wv = *reinterpret_cast<const float4*>(
                    Wm + (long long)(k0 + row) * Nn + n0 + c4);
                *reinterpret_cast<float4*>(&Bs[row][c4]) = wv;
            }
        } else {
            // W[N,K]: rows n0..n0+127, cols k0..k0+15 -> transpose into Bs[k][n]
#pragma unroll
            for (int j = 0; j < 2; j++) {
                int li  = t + j * 256;
                int row = li >> 2;
                int c4  = (li & 3) * 4;
                float4 wv = *reinterpret_cast<const float4*>(
                    Wm + (long long)(n0 + row) * K + k0 + c4);
                Bs[c4 + 0][row] = wv.x;
                Bs[c4 + 1][row] = wv.y;
                Bs[c4 + 2][row] = wv.z;
                Bs[c4 + 3][row] = wv.w;
            }
        }
        __syncthreads();

#pragma unroll
        for (int kk = 0; kk < 16; kk++) {
            float a[8], w[8];
            *reinterpret_cast<float4*>(&a[0]) = *reinterpret_cast<const float4*>(&As[kk][ty * 4]);
            *reinterpret_cast<float4*>(&a[4]) = *reinterpret_cast<const float4*>(&As[kk][64 + ty * 4]);
            *reinterpret_cast<float4*>(&w[0]) = *reinterpret_cast<const float4*>(&Bs[kk][tx * 4]);
            *reinterpret_cast<float4*>(&w[4]) = *reinterpret_cast<const float4*>(&Bs[kk][64 + tx * 4]);
#pragma unroll
            for (int i = 0; i < 8; i++)
#pragma unroll
                for (int j = 0; j < 8; j++)
                    acc[i][j] = fmaf(a[i], w[j], acc[i][j]);
        }
        __syncthreads();
    }

    // --- epilogue: scale, bias, activation, store
#pragma unroll
    for (int ih = 0; ih < 2; ih++) {
#pragma unroll
        for (int i = 0; i < 4; i++) {
            int r = m0 + ih * 64 + ty * 4 + i;
            if (r < M) {
#pragma unroll
                for (int jh = 0; jh < 2; jh++) {
                    int c = n0 + jh * 64 + tx * 4;
                    float o[4];
#pragma unroll
                    for (int j = 0; j < 4; j++) {
                        float x = acc[ih * 4 + i][jh * 4 + j] * scale;
                        if (bias) x += bias[c + j];
                        if (ACT == 1) x = x / (1.f + expf(-x));  // silu
                        o[j] = x;
                    }
                    *reinterpret_cast<float4*>(C + (long long)r * Nn + c) =
                        *reinterpret_cast<float4*>(o);
                }
            }
        }
    }
}

// ---------------------------------------------------------------------------
// Masked softmax over N_ATOMS, one wave (64 lanes) per (b,e) row, in place.
// Replicates: where(mask, s, -1e9) -> softmax -> * mask
// ---------------------------------------------------------------------------
__global__ __launch_bounds__(256) void softmax_kernel(
    float* __restrict__ att, const int* __restrict__ mask)
{
    int row  = blockIdx.x * 4 + (threadIdx.x >> 6);  // b*NE + e
    int lane = threadIdx.x & 63;
    if (row >= BATCH * NE) return;
    int b = row / NE;
    float*     p    = att + (long long)row * N_ATOMS;
    const int* mrow = mask + b * N_ATOMS;

    float v[8];
    int   mk[8];
    float mx = -INFINITY;
#pragma unroll
    for (int i = 0; i < 8; i++) {
        int n = lane + i * 64;
        mk[i] = mrow[n];
        float s = p[n];
        v[i] = mk[i] ? s : -1e9f;
        mx = fmaxf(mx, v[i]);
    }
#pragma unroll
    for (int off = 32; off; off >>= 1) mx = fmaxf(mx, __shfl_xor(mx, off, 64));

    float sum = 0.f;
#pragma unroll
    for (int i = 0; i < 8; i++) {
        v[i] = expf(v[i] - mx);
        sum += v[i];
    }
#pragma unroll
    for (int off = 32; off; off >>= 1) sum += __shfl_xor(sum, off, 64);

    float inv = 1.f / sum;
#pragma unroll
    for (int i = 0; i < 8; i++) {
        int n = lane + i * 64;
        p[n] = mk[i] ? v[i] * inv : 0.f;
    }
}

// ---------------------------------------------------------------------------
static inline void run_gemm(hipStream_t s, const float* A, const float* W,
                            const float* bias, float* C, int M, int Nn, int K,
                            int act, bool bt, long long sA, long long sW,
                            long long sC, int batch, float scale)
{
    dim3 grid(Nn / 128, (M + 127) / 128, batch);
    dim3 blk(256);
    if (act == 1) {
        // silu, W row-major (only combo used with act)
        hipLaunchKernelGGL((gemm_kernel<1, false>), grid, blk, 0, s, A, W, bias,
                           C, M, Nn, K, sA, sW, sC, scale);
    } else if (!bt) {
        hipLaunchKernelGGL((gemm_kernel<0, false>), grid, blk, 0, s, A, W, bias,
                           C, M, Nn, K, sA, sW, sC, scale);
    } else {
        hipLaunchKernelGGL((gemm_kernel<0, true>), grid, blk, 0, s, A, W, bias,
                           C, M, Nn, K, sA, sW, sC, scale);
    }
}

extern "C" void kernel_launch(void* const* d_in, const int* in_sizes, int n_in,
                              void* d_out, int out_size, void* d_ws, size_t ws_size,
                              hipStream_t stream)
{
    const float* field = (const float*)d_in[0];   // [64,512,256]
    const int*   mask  = (const int*)d_in[1];     // [64,512] (bool -> int)
    const float* efeat = (const float*)d_in[2];   // [500,64]
    const float* q_w1 = (const float*)d_in[3];  const float* q_b1 = (const float*)d_in[4];
    const float* q_w2 = (const float*)d_in[5];  const float* q_b2 = (const float*)d_in[6];
    const float* q_w3 = (const float*)d_in[7];  const float* q_b3 = (const float*)d_in[8];
    const float* k_w1 = (const float*)d_in[9];  const float* k_b1 = (const float*)d_in[10];
    const float* k_w2 = (const float*)d_in[11]; const float* k_b2 = (const float*)d_in[12];
    const float* k_w3 = (const float*)d_in[13]; const float* k_b3 = (const float*)d_in[14];
    const float* v_w1 = (const float*)d_in[15]; const float* v_b1 = (const float*)d_in[16];
    const float* v_w2 = (const float*)d_in[17]; const float* v_b2 = (const float*)d_in[18];
    const float* v_w3 = (const float*)d_in[19]; const float* v_b3 = (const float*)d_in[20];
    const float* o_w1 = (const float*)d_in[21]; const float* o_b1 = (const float*)d_in[22];
    const float* o_w2 = (const float*)d_in[23]; const float* o_b2 = (const float*)d_in[24];

    float* ws = (float*)d_ws;
    // workspace layout (floats)
    float* qh1  = ws;                       // 500*512   = 256000
    float* qh2  = qh1 + 256000;             // 256000
    float* qbuf = qh2 + 256000;             // 500*256   = 128000
    float* h1   = qbuf + 128000;            // 32768*512 = 16777216
    float* h2   = h1 + 16777216;            // 16777216
    float* kbuf = h2 + 16777216;            // 32768*256 = 8388608
    float* vbuf = kbuf + 8388608;           // 8388608
    // reuse: scores/attn -> h1 (needs 64*500*512 = 16384000 <= 16777216)
    // reuse: attn_out    -> h2 (needs 32000*256 =  8192000 <= 16777216)
    // reuse: o_hidden    -> h1 (needs 32000*512 = 16384000 <= 16777216)
    float* scores  = h1;
    float* attnout = h2;
    float* oh      = h1;

    const float scale = 1.0f / 16.0f;  // LATENT^-0.5 = 256^-0.5
    const int BN_ = BATCH * N_ATOMS;   // 32768
    const int BE_ = BATCH * NE;        // 32000

    // q MLP (tiny): [500,64] -> [500,512] -> [500,512] -> [500,256]
    run_gemm(stream, efeat, q_w1, q_b1, qh1, NE, HIDDEN, E_DIM,     1, false, 0, 0, 0, 1, 1.f);
    run_gemm(stream, qh1,   q_w2, q_b2, qh2, NE, HIDDEN, HIDDEN,    1, false, 0, 0, 0, 1, 1.f);
    run_gemm(stream, qh2,   q_w3, q_b3, qbuf, NE, LATENT, HIDDEN,   0, false, 0, 0, 0, 1, 1.f);

    // k MLP: [32768,256] -> 512 -> 512 -> 256
    run_gemm(stream, field, k_w1, k_b1, h1, BN_, HIDDEN, FIELD_DIM, 1, false, 0, 0, 0, 1, 1.f);
    run_gemm(stream, h1,    k_w2, k_b2, h2, BN_, HIDDEN, HIDDEN,    1, false, 0, 0, 0, 1, 1.f);
    run_gemm(stream, h2,    k_w3, k_b3, kbuf, BN_, LATENT, HIDDEN,  0, false, 0, 0, 0, 1, 1.f);

    // v MLP
    run_gemm(stream, field, v_w1, v_b1, h1, BN_, HIDDEN, FIELD_DIM, 1, false, 0, 0, 0, 1, 1.f);
    run_gemm(stream, h1,    v_w2, v_b2, h2, BN_, HIDDEN, HIDDEN,    1, false, 0, 0, 0, 1, 1.f);
    run_gemm(stream, h2,    v_w3, v_b3, vbuf, BN_, LATENT, HIDDEN,  0, false, 0, 0, 0, 1, 1.f);

    // scores[b,e,n] = scale * q[e,:] . k[b,n,:]   (A@B^T, batched over b)
    run_gemm(stream, qbuf, kbuf, nullptr, scores, NE, N_ATOMS, LATENT, 0, true,
             0, (long long)N_ATOMS * LATENT, (long long)NE * N_ATOMS, BATCH, scale);

    // masked softmax in place
    hipLaunchKernelGGL(softmax_kernel, dim3(BE_ / 4), dim3(256), 0, stream, scores, mask);

    // attn_out[b,e,:] = attn[b,e,:] @ v[b]   (batched NN)
    run_gemm(stream, scores, vbuf, nullptr, attnout, NE, LATENT, N_ATOMS, 0, false,
             (long long)NE * N_ATOMS, (long long)N_ATOMS * LATENT, (long long)NE * LATENT,
             BATCH, 1.f);

    // out MLP: [32000,256] -> silu -> [32000,512] -> [32000,256]
    run_gemm(stream, attnout, o_w1, o_b1, oh, BE_, HIDDEN, LATENT, 1, false, 0, 0, 0, 1, 1.f);
    run_gemm(stream, oh, o_w2, o_b2, (float*)d_out, BE_, LATENT, HIDDEN, 0, false, 0, 0, 0, 1, 1.f);
}

// Round 4
// 379.542 us; speedup vs baseline: 4.0709x; 4.0709x over previous
//
#include <hip/hip_runtime.h>
#include <math.h>

// Problem constants
#define BATCH 64
#define N_ATOMS 512
#define NE 500
#define FIELD_DIM 256
#define E_DIM 64
#define HIDDEN 512
#define LATENT 256

typedef short bf16x8 __attribute__((ext_vector_type(8)));
typedef unsigned short u16x8 __attribute__((ext_vector_type(8)));
typedef float f32x4 __attribute__((ext_vector_type(4)));

__device__ __forceinline__ unsigned short f2bf(float x) {
    unsigned u = __float_as_uint(x);
    unsigned r = (u + 0x7FFFu + ((u >> 16) & 1u)) >> 16;
    return (unsigned short)r;
}
__device__ __forceinline__ float bf2f(unsigned short b) {
    return __uint_as_float(((unsigned)b) << 16);
}

#define GLOAD_LDS16(gptr, lptr)                                                   \
    __builtin_amdgcn_global_load_lds(                                             \
        (const __attribute__((address_space(1))) void*)(gptr),                    \
        (__attribute__((address_space(3))) void*)(lptr), 16, 0, 0)

// ---------------------------------------------------------------------------
// bf16 MFMA GEMM: C[M,N] = act( scale*(A @ Bt^T) + bias )
//   A:  [M,K] bf16 row-major (batched via sA elements)
//   Bt: [N,K] bf16 row-major (weight pre-transposed; batched via sB)
//   C:  bf16 (OUTF32=0) or fp32 (OUTF32=1), batched via sC
// 128x128 tile, BK=64, 256 threads (4 waves, each 64x64 = 4x4 frags of
// 16x16x32). global_load_lds(16B) staging with XOR-swizzled source so the
// swizzled ds_read_b128 fragment reads are bank-conflict-free (rule 21).
// Only M may be unaligned (500); rows clamped on load, predicated on store.
// ---------------------------------------------------------------------------
template <int ACT, int OUTF32>
__global__ __launch_bounds__(256, 2) void gemm_bf16(
    const unsigned short* __restrict__ A, const unsigned short* __restrict__ Bt,
    const float* __restrict__ bias, void* __restrict__ Cv,
    int M, int N, int K, long long sA, long long sB, long long sC, float scale)
{
    __shared__ unsigned short As[128 * 64];
    __shared__ unsigned short Bs[128 * 64];

    const int t    = threadIdx.x;
    const int wave = t >> 6;
    const int lane = t & 63;
    const int m0 = blockIdx.y * 128;
    const int n0 = blockIdx.x * 128;
    const int bz = blockIdx.z;
    A  += (long long)bz * sA;
    Bt += (long long)bz * sB;

    // staging lane mapping: 8 rows per 64-lane issue, 8x16B granules per row
    const int s_row = lane >> 3;   // 0..7
    const int s_g   = lane & 7;    // granule within row's 64-k window

    // compute lane mapping
    const int wr = wave >> 1, wc = wave & 1;
    const int fr = lane & 15;      // frag row/col
    const int fq = lane >> 4;      // 0..3

    f32x4 acc[4][4];
#pragma unroll
    for (int i = 0; i < 4; i++)
#pragma unroll
        for (int j = 0; j < 4; j++) acc[i][j] = (f32x4)0.f;

    for (int k0 = 0; k0 < K; k0 += 64) {
        __syncthreads();  // protect LDS against previous iteration's readers
        // --- stage A: rows wave*32 .. +32
#pragma unroll
        for (int i = 0; i < 4; i++) {
            int r  = wave * 32 + i * 8 + s_row;
            int gr = m0 + r;
            if (gr >= M) gr = M - 1;                    // clamp (dup read, masked on store)
            int gsrc = s_g ^ (r & 7);                   // inverse-swizzled source granule
            const unsigned short* gp = A + (long long)gr * K + k0 + (gsrc << 3);
            GLOAD_LDS16(gp, As + (wave * 32 + i * 8) * 64);
        }
        // --- stage B: cols wave*32 .. +32 (N always multiple of 128)
#pragma unroll
        for (int i = 0; i < 4; i++) {
            int c    = wave * 32 + i * 8 + s_row;
            int gsrc = s_g ^ (c & 7);
            const unsigned short* gp = Bt + (long long)(n0 + c) * K + k0 + (gsrc << 3);
            GLOAD_LDS16(gp, Bs + (wave * 32 + i * 8) * 64);
        }
        __syncthreads();  // compiler drains vmcnt before barrier

        // --- compute: 2 x (8 ds_read_b128 + 16 MFMA)
#pragma unroll
        for (int ks = 0; ks < 2; ks++) {
            bf16x8 af[4], bfv[4];
            const int G = ks * 4 + fq;
#pragma unroll
            for (int mf = 0; mf < 4; mf++) {
                int row = wr * 64 + mf * 16 + fr;
                af[mf] = *reinterpret_cast<const bf16x8*>(
                    As + row * 64 + ((G ^ (row & 7)) << 3));
            }
#pragma unroll
            for (int nf = 0; nf < 4; nf++) {
                int col = wc * 64 + nf * 16 + fr;
                bfv[nf] = *reinterpret_cast<const bf16x8*>(
                    Bs + col * 64 + ((G ^ (col & 7)) << 3));
            }
#pragma unroll
            for (int mf = 0; mf < 4; mf++)
#pragma unroll
                for (int nf = 0; nf < 4; nf++)
                    acc[mf][nf] = __builtin_amdgcn_mfma_f32_16x16x32_bf16(
                        af[mf], bfv[nf], acc[mf][nf], 0, 0, 0);
        }
    }

    // --- epilogue: C row = m0+wr*64+mf*16+fq*4+j, col = n0+wc*64+nf*16+fr
#pragma unroll
    for (int mf = 0; mf < 4; mf++) {
        int row0 = m0 + wr * 64 + mf * 16 + fq * 4;
#pragma unroll
        for (int nf = 0; nf < 4; nf++) {
            int col  = n0 + wc * 64 + nf * 16 + fr;
            float bv = bias ? bias[col] : 0.f;
#pragma unroll
            for (int j = 0; j < 4; j++) {
                int row = row0 + j;
                if (row < M) {
                    float x = acc[mf][nf][j] * scale + bv;
                    if (ACT == 1) x = x / (1.f + __expf(-x));  // silu
                    if (OUTF32)
                        ((float*)Cv)[(long long)bz * sC + (long long)row * N + col] = x;
                    else
                        ((unsigned short*)Cv)[(long long)bz * sC + (long long)row * N + col] = f2bf(x);
                }
            }
        }
    }
}

// ---------------------------------------------------------------------------
// fp32 -> bf16 elementwise convert (n8 = n/8 vector groups)
// ---------------------------------------------------------------------------
__global__ __launch_bounds__(256) void f32_to_bf16(
    const float* __restrict__ in, unsigned short* __restrict__ out, long long n8)
{
    long long i      = (long long)blockIdx.x * 256 + threadIdx.x;
    long long stride = (long long)gridDim.x * 256;
    for (; i < n8; i += stride) {
        const float4* p = reinterpret_cast<const float4*>(in + i * 8);
        float4 a = p[0], b = p[1];
        u16x8 o;
        o[0] = f2bf(a.x); o[1] = f2bf(a.y); o[2] = f2bf(a.z); o[3] = f2bf(a.w);
        o[4] = f2bf(b.x); o[5] = f2bf(b.y); o[6] = f2bf(b.z); o[7] = f2bf(b.w);
        *reinterpret_cast<u16x8*>(out + i * 8) = o;
    }
}

// ---------------------------------------------------------------------------
// All 11 weights: W[K,N] fp32 -> Wt[N,K] bf16, one launch, z = weight id.
// ---------------------------------------------------------------------------
__global__ __launch_bounds__(256) void wt_all(
    const float* w0, const float* w1, const float* w2, const float* w3,
    const float* w4, const float* w5, const float* w6, const float* w7,
    const float* w8, const float* w9, const float* w10, unsigned short* dst)
{
    const int Kd[11] = {64, 512, 512, 256, 512, 512, 256, 512, 512, 256, 512};
    const int Nd[11] = {512, 512, 256, 512, 512, 256, 512, 512, 256, 512, 256};
    const long long Od[11] = {0, 32768, 294912, 425984, 557056, 819200,
                              950272, 1081344, 1343488, 1474560, 1605632};
    const int z = blockIdx.z;
    const float* src = z == 0 ? w0 : z == 1 ? w1 : z == 2 ? w2 : z == 3 ? w3 :
                       z == 4 ? w4 : z == 5 ? w5 : z == 6 ? w6 : z == 7 ? w7 :
                       z == 8 ? w8 : z == 9 ? w9 : w10;
    const int K = Kd[z], N = Nd[z];
    const int k0 = blockIdx.y * 64, n0 = blockIdx.x * 64;
    if (k0 >= K || n0 >= N) return;

    __shared__ float tf[64][65];
    const int t = threadIdx.x;
    const int r = t >> 2;          // 0..63
    const int c0 = (t & 3) * 16;   // 0,16,32,48

    const float* srow = src + (long long)(k0 + r) * N + n0 + c0;
#pragma unroll
    for (int q = 0; q < 4; q++) {
        float4 xv = *reinterpret_cast<const float4*>(srow + q * 4);
        tf[r][c0 + q * 4 + 0] = xv.x;
        tf[r][c0 + q * 4 + 1] = xv.y;
        tf[r][c0 + q * 4 + 2] = xv.z;
        tf[r][c0 + q * 4 + 3] = xv.w;
    }
    __syncthreads();
    unsigned short* drow = dst + Od[z] + (long long)(n0 + r) * K + k0 + c0;
    u16x8 o0, o1;
#pragma unroll
    for (int j = 0; j < 8; j++) {
        o0[j] = f2bf(tf[c0 + j][r]);
        o1[j] = f2bf(tf[c0 + 8 + j][r]);
    }
    *reinterpret_cast<u16x8*>(drow)     = o0;
    *reinterpret_cast<u16x8*>(drow + 8) = o1;
}

// ---------------------------------------------------------------------------
// v [64][512][256] bf16 -> vt [64][256][512] bf16 (per-batch transpose)
// ---------------------------------------------------------------------------
__global__ __launch_bounds__(256) void transpose_v(
    const unsigned short* __restrict__ v, unsigned short* __restrict__ vt)
{
    __shared__ unsigned short tile[64][72];
    const int b  = blockIdx.z;
    const int a0 = blockIdx.y * 64;   // atom tile
    const int l0 = blockIdx.x * 64;   // latent tile
    const int t  = threadIdx.x;
    const int r  = t >> 2;
    const int c0 = (t & 3) * 16;

    const unsigned short* src = v + ((long long)b * N_ATOMS + a0 + r) * LATENT + l0 + c0;
    u16x8 x0 = *reinterpret_cast<const u16x8*>(src);
    u16x8 x1 = *reinterpret_cast<const u16x8*>(src + 8);
#pragma unroll
    for (int j = 0; j < 8; j++) {
        tile[c0 + j][r]     = x0[j];
        tile[c0 + 8 + j][r] = x1[j];
    }
    __syncthreads();
    unsigned short* drow = vt + ((long long)b * LATENT + l0 + r) * N_ATOMS + a0 + c0;
    u16x8 y0, y1;
#pragma unroll
    for (int j = 0; j < 8; j++) {
        y0[j] = tile[r][c0 + j];
        y1[j] = tile[r][c0 + 8 + j];
    }
    *reinterpret_cast<u16x8*>(drow)     = y0;
    *reinterpret_cast<u16x8*>(drow + 8) = y1;
}

// ---------------------------------------------------------------------------
// Masked softmax over N_ATOMS=512, one wave per (b,e) row, bf16 in place.
// ---------------------------------------------------------------------------
__global__ __launch_bounds__(256) void softmax_bf16(
    unsigned short* __restrict__ att, const int* __restrict__ mask)
{
    const int row  = blockIdx.x * 4 + (threadIdx.x >> 6);  // b*NE + e
    const int lane = threadIdx.x & 63;
    const int b    = row / NE;
    unsigned short* p = att + (long long)row * N_ATOMS;
    const int* mrow   = mask + b * N_ATOMS;

    u16x8 sv = *reinterpret_cast<const u16x8*>(p + lane * 8);
    int4 ma  = *reinterpret_cast<const int4*>(mrow + lane * 8);
    int4 mb  = *reinterpret_cast<const int4*>(mrow + lane * 8 + 4);
    int mk[8] = {ma.x, ma.y, ma.z, ma.w, mb.x, mb.y, mb.z, mb.w};

    float v[8];
    float mx = -INFINITY;
#pragma unroll
    for (int i = 0; i < 8; i++) {
        v[i] = mk[i] ? bf2f(sv[i]) : -1e9f;
        mx = fmaxf(mx, v[i]);
    }
#pragma unroll
    for (int off = 32; off; off >>= 1) mx = fmaxf(mx, __shfl_xor(mx, off, 64));

    float sum = 0.f;
#pragma unroll
    for (int i = 0; i < 8; i++) {
        v[i] = __expf(v[i] - mx);
        sum += v[i];
    }
#pragma unroll
    for (int off = 32; off; off >>= 1) sum += __shfl_xor(sum, off, 64);

    const float inv = 1.f / sum;
    u16x8 o;
#pragma unroll
    for (int i = 0; i < 8; i++) o[i] = mk[i] ? f2bf(v[i] * inv) : 0;
    *reinterpret_cast<u16x8*>(p + lane * 8) = o;
}

// ---------------------------------------------------------------------------
static inline void launch_gemm(hipStream_t st, const unsigned short* A,
                               const unsigned short* Bt, const float* bias,
                               void* C, int M, int N, int K, long long sA,
                               long long sB, long long sC, int batch,
                               float scale, int act, int outf32)
{
    dim3 g(N / 128, (M + 127) / 128, batch), b(256);
    if (outf32)
        gemm_bf16<0, 1><<<g, b, 0, st>>>(A, Bt, bias, C, M, N, K, sA, sB, sC, scale);
    else if (act)
        gemm_bf16<1, 0><<<g, b, 0, st>>>(A, Bt, bias, C, M, N, K, sA, sB, sC, scale);
    else
        gemm_bf16<0, 0><<<g, b, 0, st>>>(A, Bt, bias, C, M, N, K, sA, sB, sC, scale);
}

extern "C" void kernel_launch(void* const* d_in, const int* in_sizes, int n_in,
                              void* d_out, int out_size, void* d_ws, size_t ws_size,
                              hipStream_t stream)
{
    const float* field = (const float*)d_in[0];   // [64,512,256] = 8,388,608 f32
    const int*   mask  = (const int*)d_in[1];     // [64,512]
    const float* efeat = (const float*)d_in[2];   // [500,64] = 32,000 f32
    const float* q_w1 = (const float*)d_in[3];  const float* q_b1 = (const float*)d_in[4];
    const float* q_w2 = (const float*)d_in[5];  const float* q_b2 = (const float*)d_in[6];
    const float* q_w3 = (const float*)d_in[7];  const float* q_b3 = (const float*)d_in[8];
    const float* k_w1 = (const float*)d_in[9];  const float* k_b1 = (const float*)d_in[10];
    const float* k_w2 = (const float*)d_in[11]; const float* k_b2 = (const float*)d_in[12];
    const float* k_w3 = (const float*)d_in[13]; const float* k_b3 = (const float*)d_in[14];
    const float* v_w1 = (const float*)d_in[15]; const float* v_b1 = (const float*)d_in[16];
    const float* v_w2 = (const float*)d_in[17]; const float* v_b2 = (const float*)d_in[18];
    const float* v_w3 = (const float*)d_in[19]; const float* v_b3 = (const float*)d_in[20];
    const float* o_w1 = (const float*)d_in[21]; const float* o_b1 = (const float*)d_in[22];
    const float* o_w2 = (const float*)d_in[23]; const float* o_b2 = (const float*)d_in[24];

    // workspace layout (ushort units, all 16B aligned)
    const long long FIELD_ELEMS = 8388608;  // 64*512*256
    unsigned short* ws = (unsigned short*)d_ws;
    unsigned short* field_bf = ws;                       // 8,388,608
    unsigned short* efeat_bf = field_bf + FIELD_ELEMS;   // 32,000
    unsigned short* wt       = efeat_bf + 32000;         // 1,736,704
    unsigned short* qh1      = wt + 1736704;             // 256,000
    unsigned short* qh2      = qh1 + 256000;             // 256,000
    unsigned short* qbuf     = qh2 + 256000;             // 128,000
    unsigned short* h1       = qbuf + 128000;            // 16,777,216
    unsigned short* h2       = h1 + 16777216;            // 16,777,216
    unsigned short* kbuf     = h2 + 16777216;            // 8,388,608
    unsigned short* vbuf     = kbuf + 8388608;           // 8,388,608
    unsigned short* vt       = vbuf + 8388608;           // 8,388,608
    // reuse: scores/attn -> h1 (64*500*512 = 16,384,000); attnout -> h2; oh -> h1

    const float scale = 1.0f / 16.0f;  // LATENT^-0.5
    const int BN_ = BATCH * N_ATOMS;   // 32768
    const int BE_ = BATCH * NE;        // 32000

    // --- input conversions + weight transpose-convert
    f32_to_bf16<<<dim3(2048), dim3(256), 0, stream>>>(field, field_bf, FIELD_ELEMS / 8);
    f32_to_bf16<<<dim3(16),   dim3(256), 0, stream>>>(efeat, efeat_bf, 32000 / 8);
    wt_all<<<dim3(8, 8, 11), dim3(256), 0, stream>>>(
        q_w1, q_w2, q_w3, k_w1, k_w2, k_w3, v_w1, v_w2, v_w3, o_w1, o_w2, wt);

    // weight offsets in wt
    unsigned short* qw1t = wt;            // [512][64]
    unsigned short* qw2t = wt + 32768;    // [512][512]
    unsigned short* qw3t = wt + 294912;   // [256][512]
    unsigned short* kw1t = wt + 425984;   // [512][256]
    unsigned short* kw2t = wt + 557056;   // [512][512]
    unsigned short* kw3t = wt + 819200;   // [256][512]
    unsigned short* vw1t = wt + 950272;
    unsigned short* vw2t = wt + 1081344;
    unsigned short* vw3t = wt + 1343488;
    unsigned short* ow1t = wt + 1474560;  // [512][256]
    unsigned short* ow2t = wt + 1605632;  // [256][512]

    // --- q MLP (tiny)
    launch_gemm(stream, efeat_bf, qw1t, q_b1, qh1, NE, HIDDEN, E_DIM, 0, 0, 0, 1, 1.f, 1, 0);
    launch_gemm(stream, qh1, qw2t, q_b2, qh2, NE, HIDDEN, HIDDEN, 0, 0, 0, 1, 1.f, 1, 0);
    launch_gemm(stream, qh2, qw3t, q_b3, qbuf, NE, LATENT, HIDDEN, 0, 0, 0, 1, 1.f, 0, 0);

    // --- k MLP
    launch_gemm(stream, field_bf, kw1t, k_b1, h1, BN_, HIDDEN, FIELD_DIM, 0, 0, 0, 1, 1.f, 1, 0);
    launch_gemm(stream, h1, kw2t, k_b2, h2, BN_, HIDDEN, HIDDEN, 0, 0, 0, 1, 1.f, 1, 0);
    launch_gemm(stream, h2, kw3t, k_b3, kbuf, BN_, LATENT, HIDDEN, 0, 0, 0, 1, 1.f, 0, 0);

    // --- v MLP
    launch_gemm(stream, field_bf, vw1t, v_b1, h1, BN_, HIDDEN, FIELD_DIM, 0, 0, 0, 1, 1.f, 1, 0);
    launch_gemm(stream, h1, vw2t, v_b2, h2, BN_, HIDDEN, HIDDEN, 0, 0, 0, 1, 1.f, 1, 0);
    launch_gemm(stream, h2, vw3t, v_b3, vbuf, BN_, LATENT, HIDDEN, 0, 0, 0, 1, 1.f, 0, 0);

    // --- v transpose for PV ([b][latent][atom])
    transpose_v<<<dim3(4, 8, 64), dim3(256), 0, stream>>>(vbuf, vt);

    // --- QK^T: scores[b,e,n] = scale * q[e,:] . k[b,n,:]
    launch_gemm(stream, qbuf, kbuf, nullptr, h1, NE, N_ATOMS, LATENT,
                0, (long long)N_ATOMS * LATENT, (long long)NE * N_ATOMS,
                BATCH, scale, 0, 0);

    // --- masked softmax (in place, bf16)
    softmax_bf16<<<dim3(BE_ / 4), dim3(256), 0, stream>>>(h1, mask);

    // --- PV: attnout[b,e,l] = attn[b,e,:] . vt[b,l,:]
    launch_gemm(stream, h1, vt, nullptr, h2, NE, LATENT, N_ATOMS,
                (long long)NE * N_ATOMS, (long long)LATENT * N_ATOMS,
                (long long)NE * LATENT, BATCH, 1.f, 0, 0);

    // --- out MLP
    launch_gemm(stream, h2, ow1t, o_b1, h1, BE_, HIDDEN, LATENT, 0, 0, 0, 1, 1.f, 1, 0);
    launch_gemm(stream, h1, ow2t, o_b2, d_out, BE_, LATENT, HIDDEN, 0, 0, 0, 1, 1.f, 0, 1);
}

// Round 5
// 350.198 us; speedup vs baseline: 4.4120x; 1.0838x over previous
//
#include <hip/hip_runtime.h>
#include <math.h>

// Problem constants
#define BATCH 64
#define N_ATOMS 512
#define NE 500
#define FIELD_DIM 256
#define E_DIM 64
#define HIDDEN 512
#define LATENT 256

typedef short bf16x8 __attribute__((ext_vector_type(8)));
typedef unsigned short u16x8 __attribute__((ext_vector_type(8)));
typedef float f32x4 __attribute__((ext_vector_type(4)));

__device__ __forceinline__ unsigned short f2bf(float x) {
    unsigned u = __float_as_uint(x);
    unsigned r = (u + 0x7FFFu + ((u >> 16) & 1u)) >> 16;
    return (unsigned short)r;
}
__device__ __forceinline__ float bf2f(unsigned short b) {
    return __uint_as_float(((unsigned)b) << 16);
}

#define GLOAD_LDS16(gptr, lptr)                                                   \
    __builtin_amdgcn_global_load_lds(                                             \
        (const __attribute__((address_space(1))) void*)(gptr),                    \
        (__attribute__((address_space(3))) void*)(lptr), 16, 0, 0)

// ---------------------------------------------------------------------------
// bf16 MFMA GEMM: C[M,N] = act( scale*(A @ Bt^T) + bias )
//   A:  [M,K] bf16, row stride lda (so column slices of wider buffers work)
//   Bt: [N,K] bf16 row-major (weight pre-transposed)
//   C:  bf16 (OUTF32=0) or fp32 (OUTF32=1)
// 128x128 tile, BK=64, 4 waves x (4x4 frags of 16x16x32), swizzled
// global_load_lds staging (rule 21: linear dest + inv-swizzled src + swz read).
// ---------------------------------------------------------------------------
template <int ACT, int OUTF32>
__global__ __launch_bounds__(256, 2) void gemm_bf16(
    const unsigned short* __restrict__ A, const unsigned short* __restrict__ Bt,
    const float* __restrict__ bias, void* __restrict__ Cv,
    int M, int N, int K, int lda, float scale)
{
    __shared__ unsigned short As[128 * 64];
    __shared__ unsigned short Bs[128 * 64];

    const int t    = threadIdx.x;
    const int wave = t >> 6;
    const int lane = t & 63;
    const int m0 = blockIdx.y * 128;
    const int n0 = blockIdx.x * 128;

    const int s_row = lane >> 3;   // 0..7
    const int s_g   = lane & 7;    // granule

    const int wr = wave >> 1, wc = wave & 1;
    const int fr = lane & 15;
    const int fq = lane >> 4;

    f32x4 acc[4][4];
#pragma unroll
    for (int i = 0; i < 4; i++)
#pragma unroll
        for (int j = 0; j < 4; j++) acc[i][j] = (f32x4)0.f;

    for (int k0 = 0; k0 < K; k0 += 64) {
        __syncthreads();
#pragma unroll
        for (int i = 0; i < 4; i++) {
            int r  = wave * 32 + i * 8 + s_row;
            int gr = m0 + r;
            if (gr >= M) gr = M - 1;
            int gsrc = s_g ^ (r & 7);
            GLOAD_LDS16(A + (long long)gr * lda + k0 + (gsrc << 3),
                        As + (wave * 32 + i * 8) * 64);
        }
#pragma unroll
        for (int i = 0; i < 4; i++) {
            int c    = wave * 32 + i * 8 + s_row;
            int gsrc = s_g ^ (c & 7);
            GLOAD_LDS16(Bt + (long long)(n0 + c) * K + k0 + (gsrc << 3),
                        Bs + (wave * 32 + i * 8) * 64);
        }
        __syncthreads();

#pragma unroll
        for (int ks = 0; ks < 2; ks++) {
            bf16x8 af[4], bfv[4];
            const int G = ks * 4 + fq;
#pragma unroll
            for (int mf = 0; mf < 4; mf++) {
                int row = wr * 64 + mf * 16 + fr;
                af[mf] = *reinterpret_cast<const bf16x8*>(
                    As + row * 64 + ((G ^ (row & 7)) << 3));
            }
#pragma unroll
            for (int nf = 0; nf < 4; nf++) {
                int col = wc * 64 + nf * 16 + fr;
                bfv[nf] = *reinterpret_cast<const bf16x8*>(
                    Bs + col * 64 + ((G ^ (col & 7)) << 3));
            }
#pragma unroll
            for (int mf = 0; mf < 4; mf++)
#pragma unroll
                for (int nf = 0; nf < 4; nf++)
                    acc[mf][nf] = __builtin_amdgcn_mfma_f32_16x16x32_bf16(
                        af[mf], bfv[nf], acc[mf][nf], 0, 0, 0);
        }
    }

#pragma unroll
    for (int mf = 0; mf < 4; mf++) {
        int row0 = m0 + wr * 64 + mf * 16 + fq * 4;
#pragma unroll
        for (int nf = 0; nf < 4; nf++) {
            int col  = n0 + wc * 64 + nf * 16 + fr;
            float bv = bias ? bias[col] : 0.f;
#pragma unroll
            for (int j = 0; j < 4; j++) {
                int row = row0 + j;
                if (row < M) {
                    float x = acc[mf][nf][j] * scale + bv;
                    if (ACT == 1) x = x / (1.f + __expf(-x));  // silu
                    if (OUTF32)
                        ((float*)Cv)[(long long)row * N + col] = x;
                    else
                        ((unsigned short*)Cv)[(long long)row * N + col] = f2bf(x);
                }
            }
        }
    }
}

// ---------------------------------------------------------------------------
// Fused attention: per block (b, 64-e-tile): S = scale*Q K^T, masked softmax,
// O = P V. 8 waves x 512 thr. Q[4][64][64] LDS slabs + K chunks [512][64],
// S in regs (f32), P -> swizzled LDS bf16, V^T chunks [256][64].
// ---------------------------------------------------------------------------
__global__ __launch_bounds__(512, 1) void attn_fused(
    const unsigned short* __restrict__ qbuf,   // [NE][256]
    const unsigned short* __restrict__ kbuf,   // [B][512][256]
    const unsigned short* __restrict__ vt,     // [B][256][512]
    const int* __restrict__ mask,              // [B][512]
    unsigned short* __restrict__ attnout)      // [B][NE][256]
{
    __shared__ unsigned char LDS[100352];
    unsigned short* Qs = (unsigned short*)LDS;             // [4][64][64] 32KB
    unsigned short* Ks = (unsigned short*)(LDS + 32768);   // [512][64]   64KB
    unsigned short* Ps = (unsigned short*)LDS;             // [64][512]   64KB overlay
    unsigned short* Vs = (unsigned short*)(LDS + 65536);   // [256][64]   32KB
    float*          red = (float*)(LDS + 98304);           // [64][8]

    const int id = blockIdx.x;
    const int b  = id & 63;       // ids 64 apart -> same XCD: K/V L2 reuse
    const int e0 = (id >> 6) * 64;
    const int t = threadIdx.x, wave = t >> 6;
    const int lane = t & 63, fr = lane & 15, fq = lane >> 4;
    const int tr = t >> 3, tg = t & 7;  // staging row / granule

    // ---- stage Q (4 slabs) + K chunk 0 ----
#pragma unroll
    for (int i = 0; i < 4; i++) {
        int ge = e0 + tr; if (ge >= NE) ge = NE - 1;
        int gi = tg ^ (tr & 7);
        GLOAD_LDS16(qbuf + (long long)ge * 256 + i * 64 + gi * 8,
                    Qs + i * 4096 + wave * 512);
    }
#pragma unroll
    for (int j = 0; j < 8; j++) {
        int n  = j * 64 + tr;
        int gi = tg ^ (n & 7);
        GLOAD_LDS16(kbuf + (long long)(b * 512 + n) * 256 + gi * 8,
                    Ks + j * 4096 + wave * 512);
    }
    int mk[4];
#pragma unroll
    for (int nf = 0; nf < 4; nf++) mk[nf] = mask[b * 512 + wave * 64 + nf * 16 + fr];

    f32x4 acc[4][4];
#pragma unroll
    for (int i = 0; i < 4; i++)
#pragma unroll
        for (int j = 0; j < 4; j++) acc[i][j] = (f32x4)0.f;

    __syncthreads();

    // ---- QK^T: 4 K-steps of 64 latent ----
    for (int ks = 0; ks < 4; ks++) {
#pragma unroll
        for (int h = 0; h < 2; h++) {
            bf16x8 af[4], bv[4];
#pragma unroll
            for (int mf = 0; mf < 4; mf++) {
                int e = mf * 16 + fr;
                int byo = ks * 8192 + e * 128 + ((h * 64 + fq * 16) ^ ((e & 7) << 4));
                af[mf] = *(const bf16x8*)((const char*)Qs + byo);
            }
#pragma unroll
            for (int nf = 0; nf < 4; nf++) {
                int n = wave * 64 + nf * 16 + fr;
                int byo = n * 128 + ((h * 64 + fq * 16) ^ ((n & 7) << 4));
                bv[nf] = *(const bf16x8*)((const char*)Ks + byo);
            }
#pragma unroll
            for (int mf = 0; mf < 4; mf++)
#pragma unroll
                for (int nf = 0; nf < 4; nf++)
                    acc[mf][nf] = __builtin_amdgcn_mfma_f32_16x16x32_bf16(
                        af[mf], bv[nf], acc[mf][nf], 0, 0, 0);
        }
        if (ks < 3) {
            __syncthreads();
#pragma unroll
            for (int j = 0; j < 8; j++) {
                int n  = j * 64 + tr;
                int gi = tg ^ (n & 7);
                GLOAD_LDS16(kbuf + (long long)(b * 512 + n) * 256 + (ks + 1) * 64 + gi * 8,
                            Ks + j * 4096 + wave * 512);
            }
            __syncthreads();
        }
    }

    // ---- masked softmax (exact reference semantics) ----
    const float scale = 0.0625f;  // 256^-0.5
#pragma unroll
    for (int mf = 0; mf < 4; mf++)
#pragma unroll
        for (int nf = 0; nf < 4; nf++)
#pragma unroll
            for (int r = 0; r < 4; r++)
                acc[mf][nf][r] = mk[nf] ? acc[mf][nf][r] * scale : -1e9f;

    float gm[4][4];
#pragma unroll
    for (int mf = 0; mf < 4; mf++)
#pragma unroll
        for (int r = 0; r < 4; r++) {
            float m = fmaxf(fmaxf(acc[mf][0][r], acc[mf][1][r]),
                            fmaxf(acc[mf][2][r], acc[mf][3][r]));
#pragma unroll
            for (int off = 1; off < 16; off <<= 1) m = fmaxf(m, __shfl_xor(m, off, 64));
            if (fr == 0) red[(mf * 16 + fq * 4 + r) * 8 + wave] = m;
        }
    __syncthreads();
#pragma unroll
    for (int mf = 0; mf < 4; mf++)
#pragma unroll
        for (int r = 0; r < 4; r++) {
            int row = mf * 16 + fq * 4 + r;
            float4 a = *(float4*)&red[row * 8];
            float4 c = *(float4*)&red[row * 8 + 4];
            gm[mf][r] = fmaxf(fmaxf(fmaxf(a.x, a.y), fmaxf(a.z, a.w)),
                              fmaxf(fmaxf(c.x, c.y), fmaxf(c.z, c.w)));
        }
    __syncthreads();

    float inv[4][4];
#pragma unroll
    for (int mf = 0; mf < 4; mf++)
#pragma unroll
        for (int r = 0; r < 4; r++) {
            float s = 0.f;
#pragma unroll
            for (int nf = 0; nf < 4; nf++) {
                acc[mf][nf][r] = __expf(acc[mf][nf][r] - gm[mf][r]);
                s += acc[mf][nf][r];
            }
#pragma unroll
            for (int off = 1; off < 16; off <<= 1) s += __shfl_xor(s, off, 64);
            if (fr == 0) red[(mf * 16 + fq * 4 + r) * 8 + wave] = s;
        }
    __syncthreads();
#pragma unroll
    for (int mf = 0; mf < 4; mf++)
#pragma unroll
        for (int r = 0; r < 4; r++) {
            int row = mf * 16 + fq * 4 + r;
            float4 a = *(float4*)&red[row * 8];
            float4 c = *(float4*)&red[row * 8 + 4];
            inv[mf][r] = 1.f / (a.x + a.y + a.z + a.w + c.x + c.y + c.z + c.w);
        }

    // ---- write P (bf16, swizzled) into LDS overlay ----
#pragma unroll
    for (int mf = 0; mf < 4; mf++)
#pragma unroll
        for (int nf = 0; nf < 4; nf++)
#pragma unroll
            for (int r = 0; r < 4; r++) {
                int row = mf * 16 + fq * 4 + r;
                int c   = wave * 64 + nf * 16 + fr;
                float pv = mk[nf] ? acc[mf][nf][r] * inv[mf][r] : 0.f;
                *(unsigned short*)((char*)Ps + row * 1024 + ((c * 2) ^ ((row & 7) << 4))) =
                    f2bf(pv);
            }
    __syncthreads();

    // ---- PV: 8 K-steps of 64 atoms ----
    f32x4 acc2[4][2];
#pragma unroll
    for (int i = 0; i < 4; i++)
#pragma unroll
        for (int j = 0; j < 2; j++) acc2[i][j] = (f32x4)0.f;

#pragma unroll
    for (int j = 0; j < 4; j++) {
        int l  = j * 64 + tr;
        int gi = tg ^ (l & 7);
        GLOAD_LDS16(vt + (long long)(b * 256 + l) * 512 + gi * 8,
                    Vs + j * 4096 + wave * 512);
    }
    __syncthreads();

    for (int ks = 0; ks < 8; ks++) {
#pragma unroll
        for (int h = 0; h < 2; h++) {
            bf16x8 af[4], bv[2];
#pragma unroll
            for (int mf = 0; mf < 4; mf++) {
                int e = mf * 16 + fr;
                int byo = e * 1024 + ((ks * 128 + h * 64 + fq * 16) ^ ((e & 7) << 4));
                af[mf] = *(const bf16x8*)((const char*)Ps + byo);
            }
#pragma unroll
            for (int nf = 0; nf < 2; nf++) {
                int l = wave * 32 + nf * 16 + fr;
                int byo = l * 128 + ((h * 64 + fq * 16) ^ ((l & 7) << 4));
                bv[nf] = *(const bf16x8*)((const char*)Vs + byo);
            }
#pragma unroll
            for (int mf = 0; mf < 4; mf++)
#pragma unroll
                for (int nf = 0; nf < 2; nf++)
                    acc2[mf][nf] = __builtin_amdgcn_mfma_f32_16x16x32_bf16(
                        af[mf], bv[nf], acc2[mf][nf], 0, 0, 0);
        }
        if (ks < 7) {
            __syncthreads();
#pragma unroll
            for (int j = 0; j < 4; j++) {
                int l  = j * 64 + tr;
                int gi = tg ^ (l & 7);
                GLOAD_LDS16(vt + (long long)(b * 256 + l) * 512 + (ks + 1) * 64 + gi * 8,
                            Vs + j * 4096 + wave * 512);
            }
            __syncthreads();
        }
    }

    // ---- epilogue ----
#pragma unroll
    for (int mf = 0; mf < 4; mf++)
#pragma unroll
        for (int nf = 0; nf < 2; nf++)
#pragma unroll
            for (int r = 0; r < 4; r++) {
                int e = e0 + mf * 16 + fq * 4 + r;
                if (e < NE) {
                    int l = wave * 32 + nf * 16 + fr;
                    attnout[((long long)b * NE + e) * 256 + l] = f2bf(acc2[mf][nf][r]);
                }
            }
}

// ---------------------------------------------------------------------------
__global__ __launch_bounds__(256) void f32_to_bf16(
    const float* __restrict__ in, unsigned short* __restrict__ out, long long n8)
{
    long long i      = (long long)blockIdx.x * 256 + threadIdx.x;
    long long stride = (long long)gridDim.x * 256;
    for (; i < n8; i += stride) {
        const float4* p = reinterpret_cast<const float4*>(in + i * 8);
        float4 a = p[0], b = p[1];
        u16x8 o;
        o[0] = f2bf(a.x); o[1] = f2bf(a.y); o[2] = f2bf(a.z); o[3] = f2bf(a.w);
        o[4] = f2bf(b.x); o[5] = f2bf(b.y); o[6] = f2bf(b.z); o[7] = f2bf(b.w);
        *reinterpret_cast<u16x8*>(out + i * 8) = o;
    }
}

// ---------------------------------------------------------------------------
// 11 weights W[K,N] fp32 -> Wt[N,K] bf16. Order: q1,q2,q3,k1,v1,k2,v2,k3,v3,o1,o2
// (k1/v1 adjacent so layer-1 k|v runs as one N=1024 GEMM).
// ---------------------------------------------------------------------------
__global__ __launch_bounds__(256) void wt_all(
    const float* w0, const float* w1, const float* w2, const float* w3,
    const float* w4, const float* w5, const float* w6, const float* w7,
    const float* w8, const float* w9, const float* w10, unsigned short* dst)
{
    const int Kd[11] = {64, 512, 512, 256, 256, 512, 512, 512, 512, 256, 512};
    const int Nd[11] = {512, 512, 256, 512, 512, 512, 512, 256, 256, 512, 256};
    const long long Od[11] = {0, 32768, 294912, 425984, 557056, 688128,
                              950272, 1212416, 1343488, 1474560, 1605632};
    const int z = blockIdx.z;
    const float* src = z == 0 ? w0 : z == 1 ? w1 : z == 2 ? w2 : z == 3 ? w3 :
                       z == 4 ? w4 : z == 5 ? w5 : z == 6 ? w6 : z == 7 ? w7 :
                       z == 8 ? w8 : z == 9 ? w9 : w10;
    const int K = Kd[z], N = Nd[z];
    const int k0 = blockIdx.y * 64, n0 = blockIdx.x * 64;
    if (k0 >= K || n0 >= N) return;

    __shared__ float tf[64][65];
    const int t = threadIdx.x;
    const int r = t >> 2;
    const int c0 = (t & 3) * 16;

    const float* srow = src + (long long)(k0 + r) * N + n0 + c0;
#pragma unroll
    for (int q = 0; q < 4; q++) {
        float4 xv = *reinterpret_cast<const float4*>(srow + q * 4);
        tf[r][c0 + q * 4 + 0] = xv.x;
        tf[r][c0 + q * 4 + 1] = xv.y;
        tf[r][c0 + q * 4 + 2] = xv.z;
        tf[r][c0 + q * 4 + 3] = xv.w;
    }
    __syncthreads();
    unsigned short* drow = dst + Od[z] + (long long)(n0 + r) * K + k0 + c0;
    u16x8 o0, o1;
#pragma unroll
    for (int j = 0; j < 8; j++) {
        o0[j] = f2bf(tf[c0 + j][r]);
        o1[j] = f2bf(tf[c0 + 8 + j][r]);
    }
    *reinterpret_cast<u16x8*>(drow)     = o0;
    *reinterpret_cast<u16x8*>(drow + 8) = o1;
}

__global__ __launch_bounds__(256) void concat_bias(
    const float* __restrict__ a, const float* __restrict__ b, float* __restrict__ o)
{
    int i = blockIdx.x * 256 + threadIdx.x;
    if (i < 512) o[i] = a[i];
    else if (i < 1024) o[i] = b[i - 512];
}

// ---------------------------------------------------------------------------
// v [64][512][256] bf16 -> vt [64][256][512] bf16
// ---------------------------------------------------------------------------
__global__ __launch_bounds__(256) void transpose_v(
    const unsigned short* __restrict__ v, unsigned short* __restrict__ vt)
{
    __shared__ unsigned short tile[64][72];
    const int b  = blockIdx.z;
    const int a0 = blockIdx.y * 64;
    const int l0 = blockIdx.x * 64;
    const int t  = threadIdx.x;
    const int r  = t >> 2;
    const int c0 = (t & 3) * 16;

    const unsigned short* src = v + ((long long)b * N_ATOMS + a0 + r) * LATENT + l0 + c0;
    u16x8 x0 = *reinterpret_cast<const u16x8*>(src);
    u16x8 x1 = *reinterpret_cast<const u16x8*>(src + 8);
#pragma unroll
    for (int j = 0; j < 8; j++) {
        tile[c0 + j][r]     = x0[j];
        tile[c0 + 8 + j][r] = x1[j];
    }
    __syncthreads();
    unsigned short* drow = vt + ((long long)b * LATENT + l0 + r) * N_ATOMS + a0 + c0;
    u16x8 y0, y1;
#pragma unroll
    for (int j = 0; j < 8; j++) {
        y0[j] = tile[r][c0 + j];
        y1[j] = tile[r][c0 + 8 + j];
    }
    *reinterpret_cast<u16x8*>(drow)     = y0;
    *reinterpret_cast<u16x8*>(drow + 8) = y1;
}

// ---------------------------------------------------------------------------
static inline void launch_gemm(hipStream_t st, const unsigned short* A,
                               const unsigned short* Bt, const float* bias,
                               void* C, int M, int N, int K, int lda,
                               float scale, int act, int outf32)
{
    dim3 g(N / 128, (M + 127) / 128, 1), b(256);
    if (outf32)
        gemm_bf16<0, 1><<<g, b, 0, st>>>(A, Bt, bias, C, M, N, K, lda, scale);
    else if (act)
        gemm_bf16<1, 0><<<g, b, 0, st>>>(A, Bt, bias, C, M, N, K, lda, scale);
    else
        gemm_bf16<0, 0><<<g, b, 0, st>>>(A, Bt, bias, C, M, N, K, lda, scale);
}

extern "C" void kernel_launch(void* const* d_in, const int* in_sizes, int n_in,
                              void* d_out, int out_size, void* d_ws, size_t ws_size,
                              hipStream_t stream)
{
    const float* field = (const float*)d_in[0];   // [64,512,256]
    const int*   mask  = (const int*)d_in[1];     // [64,512]
    const float* efeat = (const float*)d_in[2];   // [500,64]
    const float* q_w1 = (const float*)d_in[3];  const float* q_b1 = (const float*)d_in[4];
    const float* q_w2 = (const float*)d_in[5];  const float* q_b2 = (const float*)d_in[6];
    const float* q_w3 = (const float*)d_in[7];  const float* q_b3 = (const float*)d_in[8];
    const float* k_w1 = (const float*)d_in[9];  const float* k_b1 = (const float*)d_in[10];
    const float* k_w2 = (const float*)d_in[11]; const float* k_b2 = (const float*)d_in[12];
    const float* k_w3 = (const float*)d_in[13]; const float* k_b3 = (const float*)d_in[14];
    const float* v_w1 = (const float*)d_in[15]; const float* v_b1 = (const float*)d_in[16];
    const float* v_w2 = (const float*)d_in[17]; const float* v_b2 = (const float*)d_in[18];
    const float* v_w3 = (const float*)d_in[19]; const float* v_b3 = (const float*)d_in[20];
    const float* o_w1 = (const float*)d_in[21]; const float* o_b1 = (const float*)d_in[22];
    const float* o_w2 = (const float*)d_in[23]; const float* o_b2 = (const float*)d_in[24];

    // workspace layout (ushort units) — peak ~149 MiB
    unsigned short* ws = (unsigned short*)d_ws;
    unsigned short* field_bf = ws;                        // 8,388,608
    unsigned short* efeat_bf = ws + 8388608;              // 32,000
    unsigned short* wt       = ws + 8420608;              // 1,736,704
    float*          biaskv   = (float*)(ws + 10157312);   // 1024 f32
    unsigned short* qh1      = ws + 10159360;             // 256,000
    unsigned short* qh2      = ws + 10415360;             // 256,000
    unsigned short* qbuf     = ws + 10671360;             // 128,000
    unsigned short* h1kv     = ws + 10799360;             // 33,554,432 [32768][1024]
    unsigned short* h2k      = ws + 44353792;             // 16,777,216
    unsigned short* h2v      = ws + 61131008;             // 16,777,216
    // reuse (lifetimes disjoint):
    unsigned short* kbuf    = h1kv;                       //  8,388,608
    unsigned short* vbuf    = h1kv + 8388608;             //  8,388,608
    unsigned short* vtb     = h1kv + 16777216;            //  8,388,608
    unsigned short* attnout = h2k;                        //  8,192,000
    unsigned short* oh      = h2v;                        // 16,384,000

    const int BN_ = BATCH * N_ATOMS;  // 32768
    const int BE_ = BATCH * NE;       // 32000

    // --- conversions / weight prep
    f32_to_bf16<<<dim3(2048), dim3(256), 0, stream>>>(field, field_bf, 1048576);
    f32_to_bf16<<<dim3(16),   dim3(256), 0, stream>>>(efeat, efeat_bf, 4000);
    wt_all<<<dim3(8, 8, 11), dim3(256), 0, stream>>>(
        q_w1, q_w2, q_w3, k_w1, v_w1, k_w2, v_w2, k_w3, v_w3, o_w1, o_w2, wt);
    concat_bias<<<dim3(4), dim3(256), 0, stream>>>(k_b1, v_b1, biaskv);

    // weight offsets (new order)
    unsigned short* qw1t  = wt;             // [512][64]
    unsigned short* qw2t  = wt + 32768;     // [512][512]
    unsigned short* qw3t  = wt + 294912;    // [256][512]
    unsigned short* kv1t  = wt + 425984;    // [1024][256] (k1 ++ v1)
    unsigned short* kw2t  = wt + 688128;    // [512][512]
    unsigned short* vw2t  = wt + 950272;    // [512][512]
    unsigned short* kw3t  = wt + 1212416;   // [256][512]
    unsigned short* vw3t  = wt + 1343488;   // [256][512]
    unsigned short* ow1t  = wt + 1474560;   // [512][256]
    unsigned short* ow2t  = wt + 1605632;   // [256][512]

    // --- q MLP
    launch_gemm(stream, efeat_bf, qw1t, q_b1, qh1, NE, HIDDEN, E_DIM, E_DIM, 1.f, 1, 0);
    launch_gemm(stream, qh1, qw2t, q_b2, qh2, NE, HIDDEN, HIDDEN, HIDDEN, 1.f, 1, 0);
    launch_gemm(stream, qh2, qw3t, q_b3, qbuf, NE, LATENT, HIDDEN, HIDDEN, 1.f, 0, 0);

    // --- fused k|v layer 1: [32768,256] -> [32768,1024]
    launch_gemm(stream, field_bf, kv1t, biaskv, h1kv, BN_, 1024, FIELD_DIM, FIELD_DIM,
                1.f, 1, 0);
    // --- layer 2 (slices of h1kv, lda=1024)
    launch_gemm(stream, h1kv,       kw2t, k_b2, h2k, BN_, HIDDEN, HIDDEN, 1024, 1.f, 1, 0);
    launch_gemm(stream, h1kv + 512, vw2t, v_b2, h2v, BN_, HIDDEN, HIDDEN, 1024, 1.f, 1, 0);
    // --- layer 3
    launch_gemm(stream, h2k, kw3t, k_b3, kbuf, BN_, LATENT, HIDDEN, HIDDEN, 1.f, 0, 0);
    launch_gemm(stream, h2v, vw3t, v_b3, vbuf, BN_, LATENT, HIDDEN, HIDDEN, 1.f, 0, 0);

    // --- V^T for PV
    transpose_v<<<dim3(4, 8, 64), dim3(256), 0, stream>>>(vbuf, vtb);

    // --- fused attention (QK^T + masked softmax + PV)
    attn_fused<<<dim3(512), dim3(512), 0, stream>>>(qbuf, kbuf, vtb, mask, attnout);

    // --- out MLP
    launch_gemm(stream, attnout, ow1t, o_b1, oh, BE_, HIDDEN, LATENT, LATENT, 1.f, 1, 0);
    launch_gemm(stream, oh, ow2t, o_b2, d_out, BE_, LATENT, HIDDEN, HIDDEN, 1.f, 0, 1);
}

// Round 6
// 315.444 us; speedup vs baseline: 4.8981x; 1.1102x over previous
//
#include <hip/hip_runtime.h>
#include <math.h>

// Problem constants
#define BATCH 64
#define N_ATOMS 512
#define NE 500
#define FIELD_DIM 256
#define E_DIM 64
#define HIDDEN 512
#define LATENT 256

typedef short bf16x8 __attribute__((ext_vector_type(8)));
typedef unsigned short u16x8 __attribute__((ext_vector_type(8)));
typedef unsigned short u16x4 __attribute__((ext_vector_type(4)));
typedef float f32x4 __attribute__((ext_vector_type(4)));

__device__ __forceinline__ unsigned short f2bf(float x) {
    unsigned u = __float_as_uint(x);
    unsigned r = (u + 0x7FFFu + ((u >> 16) & 1u)) >> 16;
    return (unsigned short)r;
}
__device__ __forceinline__ float bf2f(unsigned short b) {
    return __uint_as_float(((unsigned)b) << 16);
}
__device__ __forceinline__ float silu_f(float x) { return x / (1.f + __expf(-x)); }

#define GLOAD_LDS16(gptr, lptr)                                                   \
    __builtin_amdgcn_global_load_lds(                                             \
        (const __attribute__((address_space(1))) void*)(gptr),                    \
        (__attribute__((address_space(3))) void*)(lptr), 16, 0, 0)

// ===========================================================================
// Fused MLP. Block = 512 thr (8 waves), 64 rows resident in LDS.
// Swapped MFMA operands: A = weight rows (features), B = activation rows.
//   D mapping (validated r4/r5): feature = fq*4+r (+frag base), act-row = fr.
// Mid layers: width 512, each wave computes 64 features; output written to
// LDS ping/pong ([64][512], stride 1024B, byte ^ ((row&7)<<4) swizzle).
// Weights streamed from global (L2-resident) straight into A-frag registers.
//   K_IN: layer-1 K (64 for q, 256 for k/v/o)
//   NL:   3 (q/k/v) or 2 (o; W2/B2 unused)
//   EPI:  0 = bf16 [M][256], 1 = bf16 transposed to vt[b][l][n], 2 = f32
// ===========================================================================
template <int K, int FW, bool SILU>
__device__ __forceinline__ void mlp_layer(
    const unsigned short* __restrict__ Wg, const float* __restrict__ Bg,
    const unsigned short* inb, unsigned short* outb, int wave, int fr, int fq)
{
    constexpr int MF = FW / 16;
    const int fb = wave * FW;
    f32x4 acc[MF][4];
#pragma unroll
    for (int mf = 0; mf < MF; mf++)
#pragma unroll
        for (int nf = 0; nf < 4; nf++) acc[mf][nf] = (f32x4)0.f;

#pragma unroll
    for (int ks = 0; ks < K / 32; ks++) {
        bf16x8 wf[MF], bfr[4];
#pragma unroll
        for (int mf = 0; mf < MF; mf++)
            wf[mf] = *reinterpret_cast<const bf16x8*>(
                Wg + (long long)(fb + mf * 16 + fr) * K + ks * 32 + fq * 8);
#pragma unroll
        for (int nf = 0; nf < 4; nf++) {
            int row = nf * 16 + fr;
            bfr[nf] = *reinterpret_cast<const bf16x8*>(
                (const char*)inb + row * (K * 2) +
                ((ks * 64 + fq * 16) ^ ((row & 7) << 4)));
        }
#pragma unroll
        for (int mf = 0; mf < MF; mf++)
#pragma unroll
            for (int nf = 0; nf < 4; nf++)
                acc[mf][nf] = __builtin_amdgcn_mfma_f32_16x16x32_bf16(
                    wf[mf], bfr[nf], acc[mf][nf], 0, 0, 0);
    }

    // write [64][512] (stride 1024B), 8B per (mf,nf), swizzled
#pragma unroll
    for (int mf = 0; mf < MF; mf++) {
        f32x4 bv = *reinterpret_cast<const f32x4*>(Bg + fb + mf * 16 + fq * 4);
#pragma unroll
        for (int nf = 0; nf < 4; nf++) {
            int row = nf * 16 + fr;
            u16x4 ov;
#pragma unroll
            for (int r = 0; r < 4; r++) {
                float x = acc[mf][nf][r] + bv[r];
                if (SILU) x = silu_f(x);
                ov[r] = f2bf(x);
            }
            *reinterpret_cast<u16x4*>(
                (char*)outb + row * 1024 +
                ((fb * 2 + mf * 32 + fq * 8) ^ ((row & 7) << 4))) = ov;
        }
    }
}

__device__ __forceinline__ void mlp_final512(
    const unsigned short* __restrict__ Wg, const float* __restrict__ Bg,
    const unsigned short* inb, int wave, int fr, int fq, f32x4 (&acc)[2][4])
{
    const int fb = wave * 32;
#pragma unroll
    for (int mf = 0; mf < 2; mf++)
#pragma unroll
        for (int nf = 0; nf < 4; nf++) acc[mf][nf] = (f32x4)0.f;

#pragma unroll
    for (int ks = 0; ks < 16; ks++) {
        bf16x8 wf[2], bfr[4];
#pragma unroll
        for (int mf = 0; mf < 2; mf++)
            wf[mf] = *reinterpret_cast<const bf16x8*>(
                Wg + (long long)(fb + mf * 16 + fr) * 512 + ks * 32 + fq * 8);
#pragma unroll
        for (int nf = 0; nf < 4; nf++) {
            int row = nf * 16 + fr;
            bfr[nf] = *reinterpret_cast<const bf16x8*>(
                (const char*)inb + row * 1024 +
                ((ks * 64 + fq * 16) ^ ((row & 7) << 4)));
        }
#pragma unroll
        for (int mf = 0; mf < 2; mf++)
#pragma unroll
            for (int nf = 0; nf < 4; nf++)
                acc[mf][nf] = __builtin_amdgcn_mfma_f32_16x16x32_bf16(
                    wf[mf], bfr[nf], acc[mf][nf], 0, 0, 0);
    }
#pragma unroll
    for (int mf = 0; mf < 2; mf++) {
        f32x4 bv = *reinterpret_cast<const f32x4*>(Bg + fb + mf * 16 + fq * 4);
#pragma unroll
        for (int nf = 0; nf < 4; nf++)
#pragma unroll
            for (int r = 0; r < 4; r++) acc[mf][nf][r] += bv[r];
    }
}

template <int K_IN, int NL, int EPI>
__global__ __launch_bounds__(512, 2) void fused_mlp(
    const unsigned short* __restrict__ X, int M,
    const unsigned short* __restrict__ W1, const float* __restrict__ B1,
    const unsigned short* __restrict__ W2, const float* __restrict__ B2,
    const unsigned short* __restrict__ W3, const float* __restrict__ B3,
    void* __restrict__ out)
{
    __shared__ unsigned short bufA[64 * 512];
    __shared__ unsigned short bufB[64 * 512];
    const int t = threadIdx.x, wave = t >> 6, lane = t & 63;
    const int fr = lane & 15, fq = lane >> 4;
    const int m0 = blockIdx.x * 64;

    // ---- stage X -> bufA ([64][K_IN], stride K_IN*2 B, swizzled source) ----
    constexpr int GPL = K_IN / 8;               // 16B granules per row
    constexpr int LG  = (K_IN == 64) ? 3 : 5;   // log2(GPL)
    for (int c = wave; c < GPL; c += 8) {
        int gi  = c * 64 + lane;
        int row = gi >> LG;
        int g   = gi & (GPL - 1);
        int gr  = m0 + row; if (gr >= M) gr = M - 1;
        int gs  = (g & ~7) | ((g & 7) ^ (row & 7));
        GLOAD_LDS16(X + (long long)gr * K_IN + gs * 8, bufA + c * 512);
    }
    __syncthreads();

    mlp_layer<K_IN, 64, true>(W1, B1, bufA, bufB, wave, fr, fq);
    __syncthreads();

    const unsigned short* fin;
    if constexpr (NL == 3) {
        mlp_layer<512, 64, true>(W2, B2, bufB, bufA, wave, fr, fq);
        __syncthreads();
        fin = bufA;
    } else {
        fin = bufB;
    }

    f32x4 acc[2][4];
    mlp_final512(W3, B3, fin, wave, fr, fq, acc);

    if constexpr (EPI == 0) {          // bf16 [M][256]
        unsigned short* O = (unsigned short*)out;
#pragma unroll
        for (int mf = 0; mf < 2; mf++)
#pragma unroll
            for (int nf = 0; nf < 4; nf++) {
                int row = m0 + nf * 16 + fr;
                if (row < M) {
                    u16x4 ov;
#pragma unroll
                    for (int r = 0; r < 4; r++) ov[r] = f2bf(acc[mf][nf][r]);
                    *reinterpret_cast<u16x4*>(
                        O + (long long)row * 256 + wave * 32 + mf * 16 + fq * 4) = ov;
                }
            }
    } else if constexpr (EPI == 2) {   // f32 [M][256]
        float* O = (float*)out;
#pragma unroll
        for (int mf = 0; mf < 2; mf++)
#pragma unroll
            for (int nf = 0; nf < 4; nf++) {
                int row = m0 + nf * 16 + fr;
                if (row < M)
                    *reinterpret_cast<f32x4*>(
                        O + (long long)row * 256 + wave * 32 + mf * 16 + fq * 4) =
                        acc[mf][nf];
            }
    } else {                           // EPI==1: transposed -> vt[b][256][512]
        // write tile [64 n][256 l] into bufB (free: final layer read bufA)
#pragma unroll
        for (int mf = 0; mf < 2; mf++)
#pragma unroll
            for (int nf = 0; nf < 4; nf++) {
                int row = nf * 16 + fr;
                u16x4 ov;
#pragma unroll
                for (int r = 0; r < 4; r++) ov[r] = f2bf(acc[mf][nf][r]);
                *reinterpret_cast<u16x4*>(
                    (char*)bufB + row * 512 +
                    ((wave * 64 + mf * 32 + fq * 8) ^ ((row & 7) << 4))) = ov;
            }
        __syncthreads();
        // coalesced transposed store: thread -> (l = t>>1, half-row of 32 n)
        int l  = t >> 1;
        int nh = (t & 1) * 32;
        int b  = m0 >> 9, nb = m0 & 511;
        unsigned short* O = (unsigned short*)out;
        long long base = ((long long)b * 256 + l) * 512 + nb + nh;
#pragma unroll
        for (int q = 0; q < 4; q++) {
            u16x8 ov;
#pragma unroll
            for (int j = 0; j < 8; j++) {
                int n = nh + q * 8 + j;
                ov[j] = *reinterpret_cast<const unsigned short*>(
                    (const char*)bufB + n * 512 + ((l * 2) ^ ((n & 7) << 4)));
            }
            *reinterpret_cast<u16x8*>(O + base + q * 8) = ov;
        }
    }
}

// ---------------------------------------------------------------------------
// Fused attention (unchanged from r5): per block (b, 64-e tile):
// S = scale*Q K^T, masked softmax, O = P V.
// ---------------------------------------------------------------------------
__global__ __launch_bounds__(512, 1) void attn_fused(
    const unsigned short* __restrict__ qbuf,   // [NE][256]
    const unsigned short* __restrict__ kbuf,   // [B][512][256]
    const unsigned short* __restrict__ vt,     // [B][256][512]
    const int* __restrict__ mask,              // [B][512]
    unsigned short* __restrict__ attnout)      // [B][NE][256]
{
    __shared__ unsigned char LDS[100352];
    unsigned short* Qs = (unsigned short*)LDS;             // [4][64][64] 32KB
    unsigned short* Ks = (unsigned short*)(LDS + 32768);   // [512][64]   64KB
    unsigned short* Ps = (unsigned short*)LDS;             // [64][512]   overlay
    unsigned short* Vs = (unsigned short*)(LDS + 65536);   // [256][64]   32KB
    float*          red = (float*)(LDS + 98304);           // [64][8]

    const int id = blockIdx.x;
    const int b  = id & 63;
    const int e0 = (id >> 6) * 64;
    const int t = threadIdx.x, wave = t >> 6;
    const int lane = t & 63, fr = lane & 15, fq = lane >> 4;
    const int tr = t >> 3, tg = t & 7;

#pragma unroll
    for (int i = 0; i < 4; i++) {
        int ge = e0 + tr; if (ge >= NE) ge = NE - 1;
        int gi = tg ^ (tr & 7);
        GLOAD_LDS16(qbuf + (long long)ge * 256 + i * 64 + gi * 8,
                    Qs + i * 4096 + wave * 512);
    }
#pragma unroll
    for (int j = 0; j < 8; j++) {
        int n  = j * 64 + tr;
        int gi = tg ^ (n & 7);
        GLOAD_LDS16(kbuf + (long long)(b * 512 + n) * 256 + gi * 8,
                    Ks + j * 4096 + wave * 512);
    }
    int mk[4];
#pragma unroll
    for (int nf = 0; nf < 4; nf++) mk[nf] = mask[b * 512 + wave * 64 + nf * 16 + fr];

    f32x4 acc[4][4];
#pragma unroll
    for (int i = 0; i < 4; i++)
#pragma unroll
        for (int j = 0; j < 4; j++) acc[i][j] = (f32x4)0.f;

    __syncthreads();

    for (int ks = 0; ks < 4; ks++) {
#pragma unroll
        for (int h = 0; h < 2; h++) {
            bf16x8 af[4], bv[4];
#pragma unroll
            for (int mf = 0; mf < 4; mf++) {
                int e = mf * 16 + fr;
                int byo = ks * 8192 + e * 128 + ((h * 64 + fq * 16) ^ ((e & 7) << 4));
                af[mf] = *(const bf16x8*)((const char*)Qs + byo);
            }
#pragma unroll
            for (int nf = 0; nf < 4; nf++) {
                int n = wave * 64 + nf * 16 + fr;
                int byo = n * 128 + ((h * 64 + fq * 16) ^ ((n & 7) << 4));
                bv[nf] = *(const bf16x8*)((const char*)Ks + byo);
            }
#pragma unroll
            for (int mf = 0; mf < 4; mf++)
#pragma unroll
                for (int nf = 0; nf < 4; nf++)
                    acc[mf][nf] = __builtin_amdgcn_mfma_f32_16x16x32_bf16(
                        af[mf], bv[nf], acc[mf][nf], 0, 0, 0);
        }
        if (ks < 3) {
            __syncthreads();
#pragma unroll
            for (int j = 0; j < 8; j++) {
                int n  = j * 64 + tr;
                int gi = tg ^ (n & 7);
                GLOAD_LDS16(kbuf + (long long)(b * 512 + n) * 256 + (ks + 1) * 64 + gi * 8,
                            Ks + j * 4096 + wave * 512);
            }
            __syncthreads();
        }
    }

    const float scale = 0.0625f;
#pragma unroll
    for (int mf = 0; mf < 4; mf++)
#pragma unroll
        for (int nf = 0; nf < 4; nf++)
#pragma unroll
            for (int r = 0; r < 4; r++)
                acc[mf][nf][r] = mk[nf] ? acc[mf][nf][r] * scale : -1e9f;

    float gm[4][4];
#pragma unroll
    for (int mf = 0; mf < 4; mf++)
#pragma unroll
        for (int r = 0; r < 4; r++) {
            float m = fmaxf(fmaxf(acc[mf][0][r], acc[mf][1][r]),
                            fmaxf(acc[mf][2][r], acc[mf][3][r]));
#pragma unroll
            for (int off = 1; off < 16; off <<= 1) m = fmaxf(m, __shfl_xor(m, off, 64));
            if (fr == 0) red[(mf * 16 + fq * 4 + r) * 8 + wave] = m;
        }
    __syncthreads();
#pragma unroll
    for (int mf = 0; mf < 4; mf++)
#pragma unroll
        for (int r = 0; r < 4; r++) {
            int row = mf * 16 + fq * 4 + r;
            float4 a = *(float4*)&red[row * 8];
            float4 c = *(float4*)&red[row * 8 + 4];
            gm[mf][r] = fmaxf(fmaxf(fmaxf(a.x, a.y), fmaxf(a.z, a.w)),
                              fmaxf(fmaxf(c.x, c.y), fmaxf(c.z, c.w)));
        }
    __syncthreads();

    float inv[4][4];
#pragma unroll
    for (int mf = 0; mf < 4; mf++)
#pragma unroll
        for (int r = 0; r < 4; r++) {
            float s = 0.f;
#pragma unroll
            for (int nf = 0; nf < 4; nf++) {
                acc[mf][nf][r] = __expf(acc[mf][nf][r] - gm[mf][r]);
                s += acc[mf][nf][r];
            }
#pragma unroll
            for (int off = 1; off < 16; off <<= 1) s += __shfl_xor(s, off, 64);
            if (fr == 0) red[(mf * 16 + fq * 4 + r) * 8 + wave] = s;
        }
    __syncthreads();
#pragma unroll
    for (int mf = 0; mf < 4; mf++)
#pragma unroll
        for (int r = 0; r < 4; r++) {
            int row = mf * 16 + fq * 4 + r;
            float4 a = *(float4*)&red[row * 8];
            float4 c = *(float4*)&red[row * 8 + 4];
            inv[mf][r] = 1.f / (a.x + a.y + a.z + a.w + c.x + c.y + c.z + c.w);
        }

#pragma unroll
    for (int mf = 0; mf < 4; mf++)
#pragma unroll
        for (int nf = 0; nf < 4; nf++)
#pragma unroll
            for (int r = 0; r < 4; r++) {
                int row = mf * 16 + fq * 4 + r;
                int c   = wave * 64 + nf * 16 + fr;
                float pv = mk[nf] ? acc[mf][nf][r] * inv[mf][r] : 0.f;
                *(unsigned short*)((char*)Ps + row * 1024 + ((c * 2) ^ ((row & 7) << 4))) =
                    f2bf(pv);
            }
    __syncthreads();

    f32x4 acc2[4][2];
#pragma unroll
    for (int i = 0; i < 4; i++)
#pragma unroll
        for (int j = 0; j < 2; j++) acc2[i][j] = (f32x4)0.f;

#pragma unroll
    for (int j = 0; j < 4; j++) {
        int l  = j * 64 + tr;
        int gi = tg ^ (l & 7);
        GLOAD_LDS16(vt + (long long)(b * 256 + l) * 512 + gi * 8,
                    Vs + j * 4096 + wave * 512);
    }
    __syncthreads();

    for (int ks = 0; ks < 8; ks++) {
#pragma unroll
        for (int h = 0; h < 2; h++) {
            bf16x8 af[4], bv[2];
#pragma unroll
            for (int mf = 0; mf < 4; mf++) {
                int e = mf * 16 + fr;
                int byo = e * 1024 + ((ks * 128 + h * 64 + fq * 16) ^ ((e & 7) << 4));
                af[mf] = *(const bf16x8*)((const char*)Ps + byo);
            }
#pragma unroll
            for (int nf = 0; nf < 2; nf++) {
                int l = wave * 32 + nf * 16 + fr;
                int byo = l * 128 + ((h * 64 + fq * 16) ^ ((l & 7) << 4));
                bv[nf] = *(const bf16x8*)((const char*)Vs + byo);
            }
#pragma unroll
            for (int mf = 0; mf < 4; mf++)
#pragma unroll
                for (int nf = 0; nf < 2; nf++)
                    acc2[mf][nf] = __builtin_amdgcn_mfma_f32_16x16x32_bf16(
                        af[mf], bv[nf], acc2[mf][nf], 0, 0, 0);
        }
        if (ks < 7) {
            __syncthreads();
#pragma unroll
            for (int j = 0; j < 4; j++) {
                int l  = j * 64 + tr;
                int gi = tg ^ (l & 7);
                GLOAD_LDS16(vt + (long long)(b * 256 + l) * 512 + (ks + 1) * 64 + gi * 8,
                            Vs + j * 4096 + wave * 512);
            }
            __syncthreads();
        }
    }

#pragma unroll
    for (int mf = 0; mf < 4; mf++)
#pragma unroll
        for (int nf = 0; nf < 2; nf++)
#pragma unroll
            for (int r = 0; r < 4; r++) {
                int e = e0 + mf * 16 + fq * 4 + r;
                if (e < NE) {
                    int l = wave * 32 + nf * 16 + fr;
                    attnout[((long long)b * NE + e) * 256 + l] = f2bf(acc2[mf][nf][r]);
                }
            }
}

// ---------------------------------------------------------------------------
__global__ __launch_bounds__(256) void f32_to_bf16(
    const float* __restrict__ in, unsigned short* __restrict__ out, long long n8)
{
    long long i      = (long long)blockIdx.x * 256 + threadIdx.x;
    long long stride = (long long)gridDim.x * 256;
    for (; i < n8; i += stride) {
        const float4* p = reinterpret_cast<const float4*>(in + i * 8);
        float4 a = p[0], b = p[1];
        u16x8 o;
        o[0] = f2bf(a.x); o[1] = f2bf(a.y); o[2] = f2bf(a.z); o[3] = f2bf(a.w);
        o[4] = f2bf(b.x); o[5] = f2bf(b.y); o[6] = f2bf(b.z); o[7] = f2bf(b.w);
        *reinterpret_cast<u16x8*>(out + i * 8) = o;
    }
}

// ---------------------------------------------------------------------------
// 11 weights W[K,N] fp32 -> Wt[N,K] bf16: q1,q2,q3,k1,k2,k3,v1,v2,v3,o1,o2
// ---------------------------------------------------------------------------
__global__ __launch_bounds__(256) void wt_all(
    const float* w0, const float* w1, const float* w2, const float* w3,
    const float* w4, const float* w5, const float* w6, const float* w7,
    const float* w8, const float* w9, const float* w10, unsigned short* dst)
{
    const int Kd[11] = {64, 512, 512, 256, 512, 512, 256, 512, 512, 256, 512};
    const int Nd[11] = {512, 512, 256, 512, 512, 256, 512, 512, 256, 512, 256};
    const long long Od[11] = {0, 32768, 294912, 425984, 557056, 819200,
                              950272, 1081344, 1343488, 1474560, 1605632};
    const int z = blockIdx.z;
    const float* src = z == 0 ? w0 : z == 1 ? w1 : z == 2 ? w2 : z == 3 ? w3 :
                       z == 4 ? w4 : z == 5 ? w5 : z == 6 ? w6 : z == 7 ? w7 :
                       z == 8 ? w8 : z == 9 ? w9 : w10;
    const int K = Kd[z], N = Nd[z];
    const int k0 = blockIdx.y * 64, n0 = blockIdx.x * 64;
    if (k0 >= K || n0 >= N) return;

    __shared__ float tf[64][65];
    const int t = threadIdx.x;
    const int r = t >> 2;
    const int c0 = (t & 3) * 16;

    const float* srow = src + (long long)(k0 + r) * N + n0 + c0;
#pragma unroll
    for (int q = 0; q < 4; q++) {
        float4 xv = *reinterpret_cast<const float4*>(srow + q * 4);
        tf[r][c0 + q * 4 + 0] = xv.x;
        tf[r][c0 + q * 4 + 1] = xv.y;
        tf[r][c0 + q * 4 + 2] = xv.z;
        tf[r][c0 + q * 4 + 3] = xv.w;
    }
    __syncthreads();
    unsigned short* drow = dst + Od[z] + (long long)(n0 + r) * K + k0 + c0;
    u16x8 o0, o1;
#pragma unroll
    for (int j = 0; j < 8; j++) {
        o0[j] = f2bf(tf[c0 + j][r]);
        o1[j] = f2bf(tf[c0 + 8 + j][r]);
    }
    *reinterpret_cast<u16x8*>(drow)     = o0;
    *reinterpret_cast<u16x8*>(drow + 8) = o1;
}

// ---------------------------------------------------------------------------
extern "C" void kernel_launch(void* const* d_in, const int* in_sizes, int n_in,
                              void* d_out, int out_size, void* d_ws, size_t ws_size,
                              hipStream_t stream)
{
    const float* field = (const float*)d_in[0];   // [64,512,256]
    const int*   mask  = (const int*)d_in[1];     // [64,512]
    const float* efeat = (const float*)d_in[2];   // [500,64]
    const float* q_w1 = (const float*)d_in[3];  const float* q_b1 = (const float*)d_in[4];
    const float* q_w2 = (const float*)d_in[5];  const float* q_b2 = (const float*)d_in[6];
    const float* q_w3 = (const float*)d_in[7];  const float* q_b3 = (const float*)d_in[8];
    const float* k_w1 = (const float*)d_in[9];  const float* k_b1 = (const float*)d_in[10];
    const float* k_w2 = (const float*)d_in[11]; const float* k_b2 = (const float*)d_in[12];
    const float* k_w3 = (const float*)d_in[13]; const float* k_b3 = (const float*)d_in[14];
    const float* v_w1 = (const float*)d_in[15]; const float* v_b1 = (const float*)d_in[16];
    const float* v_w2 = (const float*)d_in[17]; const float* v_b2 = (const float*)d_in[18];
    const float* v_w3 = (const float*)d_in[19]; const float* v_b3 = (const float*)d_in[20];
    const float* o_w1 = (const float*)d_in[21]; const float* o_b1 = (const float*)d_in[22];
    const float* o_w2 = (const float*)d_in[23]; const float* o_b2 = (const float*)d_in[24];

    // workspace (ushort units) — total ~70.5 MB
    unsigned short* ws = (unsigned short*)d_ws;
    unsigned short* field_bf = ws;                 // 8,388,608
    unsigned short* efeat_bf = ws + 8388608;       // 32,000
    unsigned short* wt       = ws + 8420608;       // 1,736,704
    unsigned short* qbuf     = ws + 10157312;      // 128,000
    unsigned short* kbuf     = ws + 10285312;      // 8,388,608
    unsigned short* vtb      = ws + 18673920;      // 8,388,608
    unsigned short* attnout  = ws + 27062528;      // 8,192,000

    // conversions + weight transpose
    f32_to_bf16<<<dim3(2048), dim3(256), 0, stream>>>(field, field_bf, 1048576);
    f32_to_bf16<<<dim3(16),   dim3(256), 0, stream>>>(efeat, efeat_bf, 4000);
    wt_all<<<dim3(8, 8, 11), dim3(256), 0, stream>>>(
        q_w1, q_w2, q_w3, k_w1, k_w2, k_w3, v_w1, v_w2, v_w3, o_w1, o_w2, wt);

    unsigned short* qw1t = wt;            // [512][64]
    unsigned short* qw2t = wt + 32768;    // [512][512]
    unsigned short* qw3t = wt + 294912;   // [256][512]
    unsigned short* kw1t = wt + 425984;   // [512][256]
    unsigned short* kw2t = wt + 557056;   // [512][512]
    unsigned short* kw3t = wt + 819200;   // [256][512]
    unsigned short* vw1t = wt + 950272;
    unsigned short* vw2t = wt + 1081344;
    unsigned short* vw3t = wt + 1343488;
    unsigned short* ow1t = wt + 1474560;  // [512][256]
    unsigned short* ow2t = wt + 1605632;  // [256][512]

    // fused MLPs
    fused_mlp<64, 3, 0><<<dim3(8), dim3(512), 0, stream>>>(
        efeat_bf, NE, qw1t, q_b1, qw2t, q_b2, qw3t, q_b3, qbuf);
    fused_mlp<256, 3, 0><<<dim3(512), dim3(512), 0, stream>>>(
        field_bf, BATCH * N_ATOMS, kw1t, k_b1, kw2t, k_b2, kw3t, k_b3, kbuf);
    fused_mlp<256, 3, 1><<<dim3(512), dim3(512), 0, stream>>>(
        field_bf, BATCH * N_ATOMS, vw1t, v_b1, vw2t, v_b2, vw3t, v_b3, vtb);

    // fused attention
    attn_fused<<<dim3(512), dim3(512), 0, stream>>>(qbuf, kbuf, vtb, mask, attnout);

    // out MLP (2 layers, fp32 out)
    fused_mlp<256, 2, 2><<<dim3(500), dim3(512), 0, stream>>>(
        attnout, BATCH * NE, ow1t, o_b1, nullptr, nullptr, ow2t, o_b2, d_out);
}